// Round 4
// baseline (312.775 us; speedup 1.0000x reference)
//
#include <hip/hip_runtime.h>
#include <hip/hip_bf16.h>
#include <stdint.h>

typedef __bf16 bf16x8 __attribute__((ext_vector_type(8)));
typedef float f32x4 __attribute__((ext_vector_type(4)));
typedef unsigned short u16;
typedef u16 u16x4 __attribute__((ext_vector_type(4)));
typedef uint32_t u32x4 __attribute__((ext_vector_type(4)));

#define S_LEN 2048
#define DMODEL 2048
#define NHEADS 32
#define BATCH 2
#define MROWS (BATCH * S_LEN)   // 4096
#define BIAS_LEN 1024
#define LOG2E 1.44269504088896f

// native f32->bf16 (RNE); compiler pairs these into v_cvt_pk_bf16_f32
__device__ __forceinline__ u16 b16(float f) {
  union { __bf16 h; u16 u; } cv; cv.h = (__bf16)f; return cv.u;
}

__device__ __forceinline__ void gload16(const void* g, void* l) {
  __builtin_amdgcn_global_load_lds(
      (const __attribute__((address_space(1))) uint32_t*)g,
      (__attribute__((address_space(3))) uint32_t*)l, 16, 0, 0);
}

// ---------------- f32 -> bf16 conversion ----------------
__global__ __launch_bounds__(256)
void cvt_bf16(const float* __restrict__ in, u16* __restrict__ out, int n) {
  int i = (blockIdx.x * 256 + threadIdx.x) * 4;
  if (i >= n) return;
  float4 v = *(const float4*)(in + i);
  u16x4 o = { b16(v.x), b16(v.y), b16(v.z), b16(v.w) };
  *(u16x4*)(out + i) = o;
}

// ---------------- RoPE cos/sin tables [S][32] ----------------
__global__ __launch_bounds__(256)
void rope_tab(float* __restrict__ ct, float* __restrict__ st) {
  int idx = blockIdx.x * 256 + threadIdx.x;
  if (idx >= S_LEN * 32) return;
  int s = idx >> 5, d = idx & 31;
  float inv = exp2f((float)d * (-13.287712379549449f / 32.0f));
  float a = (float)s * inv;
  ct[idx] = cosf(a);
  st[idx] = sinf(a);
}

// ---------------- GEMM: C = A(MxK) * B(NxK)^T, bf16 in, fused epilogues ----
// EPI 1: RoPE + (0.125*log2e) scale, store q [B,H,S,D] bf16
// EPI 2: RoPE, store k [B,H,S,D] bf16
// EPI 3: transpose-store v^T [B,H,D,S] bf16
// EPI 4: plain f32 store [M][N]
template<int EPI>
__global__ __launch_bounds__(256)
void gemm_bt(const u16* __restrict__ A, const u16* __restrict__ Bm,
             void* __restrict__ Cout,
             const float* __restrict__ ctab, const float* __restrict__ stab)
{
  __shared__ u16 sA[128 * 64];
  __shared__ u16 sB[128 * 64];
  const int tid  = threadIdx.x;
  const int lane = tid & 63;
  const int wid  = tid >> 6;
  const int wm   = wid >> 1, wn = wid & 1;
  const int lc   = lane & 15, lr = lane >> 4;
  const int tm   = blockIdx.y * 128;
  const int tn   = blockIdx.x * 128;

  f32x4 acc[4][4] = {};

  const u16* aS[4]; const u16* bS[4];
#pragma unroll
  for (int it = 0; it < 4; ++it) {
    int u = it * 256 + tid;
    int row = u >> 3;
    int ch  = (u & 7) ^ (row & 7);
    aS[it] = A  + (size_t)(tm + row) * DMODEL + ch * 8;
    bS[it] = Bm + (size_t)(tn + row) * DMODEL + ch * 8;
  }

  for (int k0 = 0; k0 < DMODEL; k0 += 64) {
    __syncthreads();
#pragma unroll
    for (int it = 0; it < 4; ++it) {
      int u = it * 256 + tid;
      gload16(aS[it] + k0, (char*)sA + u * 16);
      gload16(bS[it] + k0, (char*)sB + u * 16);
    }
    __syncthreads();
#pragma unroll
    for (int kk = 0; kk < 2; ++kk) {
      bf16x8 af[4], bq[4];
#pragma unroll
      for (int mi = 0; mi < 4; ++mi) {
        int row = wm * 64 + mi * 16 + lc;
        int ch  = (kk * 4 + lr) ^ (row & 7);
        af[mi] = *(const bf16x8*)((const char*)sA + row * 128 + ch * 16);
      }
#pragma unroll
      for (int ni = 0; ni < 4; ++ni) {
        int row = wn * 64 + ni * 16 + lc;
        int ch  = (kk * 4 + lr) ^ (row & 7);
        bq[ni] = *(const bf16x8*)((const char*)sB + row * 128 + ch * 16);
      }
#pragma unroll
      for (int mi = 0; mi < 4; ++mi)
#pragma unroll
        for (int ni = 0; ni < 4; ++ni)
          acc[mi][ni] = __builtin_amdgcn_mfma_f32_16x16x32_bf16(af[mi], bq[ni], acc[mi][ni], 0, 0, 0);
    }
  }

  if constexpr (EPI == 4) {
    float* C = (float*)Cout;
#pragma unroll
    for (int mi = 0; mi < 4; ++mi)
#pragma unroll
      for (int ni = 0; ni < 4; ++ni)
#pragma unroll
        for (int j = 0; j < 4; ++j) {
          int r = tm + wm * 64 + mi * 16 + lr * 4 + j;
          int c = tn + wn * 64 + ni * 16 + lc;
          C[(size_t)r * DMODEL + c] = acc[mi][ni][j];
        }
  } else if constexpr (EPI == 3) {
    u16* C = (u16*)Cout;   // v^T [B,H,D,S]
#pragma unroll
    for (int mi = 0; mi < 4; ++mi)
#pragma unroll
      for (int ni = 0; ni < 4; ++ni) {
        int col = tn + wn * 64 + ni * 16 + lc;
        int hh = col >> 6, d = col & 63;
        int m0 = tm + wm * 64 + mi * 16 + lr * 4;
        int bb = m0 >> 11, s = m0 & 2047;
        u16x4 v = { b16(acc[mi][ni][0]), b16(acc[mi][ni][1]),
                    b16(acc[mi][ni][2]), b16(acc[mi][ni][3]) };
        *(u16x4*)(C + (((size_t)bb * NHEADS + hh) * 64 + d) * S_LEN + s) = v;
      }
  } else {
    u16* C = (u16*)Cout;   // q/k [B,H,S,D], RoPE fused
#pragma unroll
    for (int mi = 0; mi < 4; ++mi)
#pragma unroll
      for (int ni = 0; ni < 2; ++ni)
#pragma unroll
        for (int j = 0; j < 4; ++j) {
          int col = tn + wn * 64 + ni * 16 + lc;
          int hh = col >> 6, dl = col & 63;
          int r = tm + wm * 64 + mi * 16 + lr * 4 + j;
          int bb = r >> 11, s = r & 2047;
          float x1 = acc[mi][ni][j], x2 = acc[mi][ni + 2][j];
          float cv = ctab[s * 32 + dl], sv = stab[s * 32 + dl];
          float o1 = x1 * cv - x2 * sv;
          float o2 = x1 * sv + x2 * cv;
          if constexpr (EPI == 1) {   // softmax scale * log2e folded into q
            o1 *= 0.125f * LOG2E; o2 *= 0.125f * LOG2E;
          }
          size_t base = (((size_t)bb * NHEADS + hh) * S_LEN + s) * 64 + dl;
          C[base]      = b16(o1);
          C[base + 32] = b16(o2);
        }
  }
}

// ---------------- fused causal attention with banded bias ----------------
// Swapped QK^T (lane holds one q-row), exp2-domain softmax, in-register P
// (ds_bpermute redistribution, no LDS P tile), XCD-aware block remap,
// balanced (31-pi, pi) pairing with shared KV sweep, T13 defer-rescale.
__global__ __launch_bounds__(512, 6)
void attn_kernel(const u16* __restrict__ Q, const u16* __restrict__ K,
                 const u16* __restrict__ V, const float* __restrict__ biasg,
                 const float* __restrict__ offg, u16* __restrict__ O)
{
  __shared__ __align__(16) u16 sK[2][64 * 64];
  __shared__ __align__(16) u16 sV[2][64 * 64];
  __shared__ float sBias[BIAS_LEN];

  const int tid = threadIdx.x, lane = tid & 63, wid = tid >> 6;
  const int lc = lane & 15, lr = lane >> 4;

  // XCD-aware remap: same-bh blocks land on one XCD (L2 fit); pi=0 first.
  const int L   = blockIdx.x;
  const int idx = L >> 3;
  const int pi  = idx >> 3;                 // 0..15
  const int bh  = (L & 7) + 8 * (idx & 7);  // 0..63
  const int h  = bh & 31;
  const int b  = bh >> 5;
  const int qtA  = 31 - pi;
  const int myQt = (wid < 4) ? qtA : pi;
  const int qw   = myQt * 64 + (wid & 3) * 16;   // wave's 16-row q base

  for (int i = tid; i < BIAS_LEN; i += 512) sBias[i] = biasg[h * BIAS_LEN + i] * LOG2E;
  const float off = offg[h] * LOG2E;

  // Q fragments (RoPE'd, scaled by 0.125*log2e). MFMA B-operand (swapped).
  const u16* qp = Q + ((size_t)bh * S_LEN + qw + lc) * 64;
  bf16x8 aq0 = *(const bf16x8*)(qp + lr * 8);
  bf16x8 aq1 = *(const bf16x8*)(qp + 32 + lr * 8);

  const int srow = tid >> 3;
  const int sch  = (tid & 7) ^ (srow & 7);
  const u16* kSrc = K + ((size_t)bh * S_LEN + srow) * 64 + sch * 8;
  const u16* vSrc = V + ((size_t)bh * 64 + srow) * S_LEN + sch * 8;

  float m = off, lsum = 1.0f;        // per-lane scalars for q = qw + lc (log2 domain)
  f32x4 o[4] = {};

  // bpermute byte-indices for the P C-layout -> A-layout move
  const int idx0 = (lc + 16 * ((lr & 1) * 2)) << 2;
  const int idx1 = idx0 + 64;
  const bool fhi = (lr >> 1) != 0;

  gload16(kSrc, (char*)sK[0] + tid * 16);
  gload16(vSrc, (char*)sV[0] + tid * 16);
  __syncthreads();

  for (int t = 0; t <= qtA; ++t) {
    const int cur = t & 1;
    if (t < qtA) {
      gload16(kSrc + (size_t)(t + 1) * 64 * 64, (char*)sK[cur ^ 1] + tid * 16);
      gload16(vSrc + (t + 1) * 64,              (char*)sV[cur ^ 1] + tid * 16);
    }

    if (t <= myQt) {
      const int kt = t * 64;
      // QK^T swapped: S^T[k][q] = K_rows x Q^T.
      f32x4 sc[4];
      __builtin_amdgcn_s_setprio(1);
#pragma unroll
      for (int f = 0; f < 4; ++f) {
        int row = f * 16 + lc;
        bf16x8 k0 = *(const bf16x8*)((const char*)sK[cur] + row * 128 + ((lr) ^ (row & 7)) * 16);
        bf16x8 k1 = *(const bf16x8*)((const char*)sK[cur] + row * 128 + ((4 + lr) ^ (row & 7)) * 16);
        f32x4 z = {};
        z     = __builtin_amdgcn_mfma_f32_16x16x32_bf16(k0, aq0, z, 0, 0, 0);
        sc[f] = __builtin_amdgcn_mfma_f32_16x16x32_bf16(k1, aq1, z, 0, 0, 0);
      }
      __builtin_amdgcn_s_setprio(0);

      // lane's q = qw + lc;  k = kt + koff,  koff = f*16 + lr*4 + j
      const int db  = qw + lc - kt;
      const int dqt = qw - kt;          // wave-uniform, multiple of 16
      float pvv[4][4];
      if (t == myQt) {                  // diagonal: causal mask, always in-band
#pragma unroll
        for (int f = 0; f < 4; ++f)
#pragma unroll
          for (int j = 0; j < 4; ++j) {
            int dd = db - (f * 16 + lr * 4 + j);
            float bb = sBias[dd & 1023];
            pvv[f][j] = (dd >= 0) ? sc[f][j] + bb : -1e30f;
          }
      } else if (dqt <= 1008) {         // interior, fully in-band: bias only
#pragma unroll
        for (int f = 0; f < 4; ++f)
#pragma unroll
          for (int j = 0; j < 4; ++j)
            pvv[f][j] = sc[f][j] + sBias[db - (f * 16 + lr * 4 + j)];
      } else if (dqt < 1088) {          // band edge: clip check only
#pragma unroll
        for (int f = 0; f < 4; ++f)
#pragma unroll
          for (int j = 0; j < 4; ++j) {
            int dd = db - (f * 16 + lr * 4 + j);
            float bb = (dd < 1024) ? sBias[dd & 1023] : 0.0f;
            pvv[f][j] = sc[f][j] + bb;
          }
      } else {                          // beyond band: raw scores
#pragma unroll
        for (int f = 0; f < 4; ++f)
#pragma unroll
          for (int j = 0; j < 4; ++j)
            pvv[f][j] = sc[f][j];
      }

      // row max: in-register tree + 2 shallow cross-lane steps
      float pmax = -1e30f;
#pragma unroll
      for (int f = 0; f < 4; ++f) {
        float a = fmaxf(fmaxf(pvv[f][0], pvv[f][1]), fmaxf(pvv[f][2], pvv[f][3]));
        pmax = fmaxf(pmax, a);
      }
      pmax = fmaxf(pmax, __shfl_xor(pmax, 16, 64));
      pmax = fmaxf(pmax, __shfl_xor(pmax, 32, 64));

      // T13 defer-rescale (log2 domain, THR=8 -> P bounded by 2^8)
      if (__any(pmax > m + 8.0f)) {
        float mn = fmaxf(m, pmax);
        float al = exp2f(m - mn);
        m = mn;
        lsum *= al;
        float aj[4];
#pragma unroll
        for (int j = 0; j < 4; ++j) aj[j] = __shfl(al, lr * 4 + j, 64);
#pragma unroll
        for (int f2 = 0; f2 < 4; ++f2)
#pragma unroll
          for (int j = 0; j < 4; ++j) o[f2][j] *= aj[j];
      }

      // exp2 + row-sum + bf16 pack (Pp[f] = packed P for koff f*16+lr*4+{0..3})
      float rsum = 0.0f;
      uint32_t Pp[4][2];
#pragma unroll
      for (int f = 0; f < 4; ++f) {
        float p0 = exp2f(pvv[f][0] - m);
        float p1 = exp2f(pvv[f][1] - m);
        float p2 = exp2f(pvv[f][2] - m);
        float p3 = exp2f(pvv[f][3] - m);
        rsum += (p0 + p1) + (p2 + p3);
        Pp[f][0] = (uint32_t)b16(p0) | ((uint32_t)b16(p1) << 16);
        Pp[f][1] = (uint32_t)b16(p2) | ((uint32_t)b16(p3) << 16);
      }
      rsum += __shfl_xor(rsum, 16, 64);
      rsum += __shfl_xor(rsum, 32, 64);
      lsum += rsum;

      // PV: O(16q x 64d) += P(16q x 64k) * V^T.  A-frag for MFMA kk assembled
      // in-register: dest (lc,lr) element e has koff = kk*32 + lr*8 + e, held
      // by src lane (lc, (lr&1)*2 + (e>>2)) at f = 2kk + (lr>>1), j = e&3.
#pragma unroll
      for (int kk = 0; kk < 2; ++kk) {
        uint32_t wl0 = __builtin_amdgcn_ds_bpermute(idx0, (int)Pp[2 * kk][0]);
        uint32_t wl1 = __builtin_amdgcn_ds_bpermute(idx0, (int)Pp[2 * kk][1]);
        uint32_t wl2 = __builtin_amdgcn_ds_bpermute(idx1, (int)Pp[2 * kk][0]);
        uint32_t wl3 = __builtin_amdgcn_ds_bpermute(idx1, (int)Pp[2 * kk][1]);
        uint32_t wh0 = __builtin_amdgcn_ds_bpermute(idx0, (int)Pp[2 * kk + 1][0]);
        uint32_t wh1 = __builtin_amdgcn_ds_bpermute(idx0, (int)Pp[2 * kk + 1][1]);
        uint32_t wh2 = __builtin_amdgcn_ds_bpermute(idx1, (int)Pp[2 * kk + 1][0]);
        uint32_t wh3 = __builtin_amdgcn_ds_bpermute(idx1, (int)Pp[2 * kk + 1][1]);
        u32x4 aw = { fhi ? wh0 : wl0, fhi ? wh1 : wl1,
                     fhi ? wh2 : wl2, fhi ? wh3 : wl3 };
        union { u32x4 u; bf16x8 bv; } cvu; cvu.u = aw;
        bf16x8 ap = cvu.bv;
        __builtin_amdgcn_s_setprio(1);
#pragma unroll
        for (int f2 = 0; f2 < 4; ++f2) {
          int drow = f2 * 16 + lc;
          int chh = (kk * 4 + lr) ^ (drow & 7);
          bf16x8 bv = *(const bf16x8*)((const char*)sV[cur] + drow * 128 + chh * 16);
          o[f2] = __builtin_amdgcn_mfma_f32_16x16x32_bf16(ap, bv, o[f2], 0, 0, 0);
        }
        __builtin_amdgcn_s_setprio(0);
      }
    }
    __syncthreads();
  }

  // normalize + store [B,S,H,D] bf16
  float ls[4];
#pragma unroll
  for (int j = 0; j < 4; ++j) ls[j] = __shfl(lsum, lr * 4 + j, 64);
#pragma unroll
  for (int f2 = 0; f2 < 4; ++f2)
#pragma unroll
    for (int j = 0; j < 4; ++j) {
      int i = qw + lr * 4 + j;
      int d = f2 * 16 + lc;
      size_t addr = (((size_t)(b * S_LEN + i)) * NHEADS + h) * 64 + d;
      O[addr] = b16(o[f2][j] / ls[j]);
    }
}

// ---------------- launcher ----------------
extern "C" void kernel_launch(void* const* d_in, const int* in_sizes, int n_in,
                              void* d_out, int out_size, void* d_ws, size_t ws_size,
                              hipStream_t stream)
{
  const float* hs   = (const float*)d_in[0];
  const float* Wq   = (const float*)d_in[1];
  const float* Wk   = (const float*)d_in[2];
  const float* Wv   = (const float*)d_in[3];
  const float* Wo   = (const float*)d_in[4];
  const float* bias = (const float*)d_in[5];
  const float* off  = (const float*)d_in[6];

  char* p = (char*)d_ws;
  u16* hs_b = (u16*)p; p += (size_t)MROWS * DMODEL * 2;
  u16* wq_b = (u16*)p; p += (size_t)DMODEL * DMODEL * 2;
  u16* wk_b = (u16*)p; p += (size_t)DMODEL * DMODEL * 2;
  u16* wv_b = (u16*)p; p += (size_t)DMODEL * DMODEL * 2;
  u16* wo_b = (u16*)p; p += (size_t)DMODEL * DMODEL * 2;
  u16* qf   = (u16*)p; p += (size_t)MROWS * DMODEL * 2;
  u16* kf   = (u16*)p; p += (size_t)MROWS * DMODEL * 2;
  u16* vt   = (u16*)p; p += (size_t)MROWS * DMODEL * 2;
  u16* att  = (u16*)p; p += (size_t)MROWS * DMODEL * 2;
  float* ct = (float*)p; p += (size_t)S_LEN * 32 * 4;
  float* st = (float*)p; p += (size_t)S_LEN * 32 * 4;
  (void)ws_size; (void)in_sizes; (void)n_in; (void)out_size;

  cvt_bf16<<<(MROWS * DMODEL) / 1024, 256, 0, stream>>>(hs, hs_b, MROWS * DMODEL);
  cvt_bf16<<<(DMODEL * DMODEL) / 1024, 256, 0, stream>>>(Wq, wq_b, DMODEL * DMODEL);
  cvt_bf16<<<(DMODEL * DMODEL) / 1024, 256, 0, stream>>>(Wk, wk_b, DMODEL * DMODEL);
  cvt_bf16<<<(DMODEL * DMODEL) / 1024, 256, 0, stream>>>(Wv, wv_b, DMODEL * DMODEL);
  cvt_bf16<<<(DMODEL * DMODEL) / 1024, 256, 0, stream>>>(Wo, wo_b, DMODEL * DMODEL);
  rope_tab<<<(S_LEN * 32) / 256, 256, 0, stream>>>(ct, st);

  dim3 g(DMODEL / 128, MROWS / 128);
  gemm_bt<1><<<g, 256, 0, stream>>>(hs_b, wq_b, qf, ct, st);
  gemm_bt<2><<<g, 256, 0, stream>>>(hs_b, wk_b, kf, ct, st);
  gemm_bt<3><<<g, 256, 0, stream>>>(hs_b, wv_b, vt, nullptr, nullptr);
  attn_kernel<<<dim3(16 * 64), 512, 0, stream>>>(qf, kf, vt, bias, off, att);
  gemm_bt<4><<<g, 256, 0, stream>>>(att, wo_b, d_out, nullptr, nullptr);
}

// Round 5
// 304.248 us; speedup vs baseline: 1.0280x; 1.0280x over previous
//
#include <hip/hip_runtime.h>
#include <hip/hip_bf16.h>
#include <stdint.h>

typedef __bf16 bf16x8 __attribute__((ext_vector_type(8)));
typedef float f32x4 __attribute__((ext_vector_type(4)));
typedef unsigned short u16;
typedef u16 u16x4 __attribute__((ext_vector_type(4)));

#define S_LEN 2048
#define DMODEL 2048
#define NHEADS 32
#define BATCH 2
#define MROWS (BATCH * S_LEN)   // 4096
#define BIAS_LEN 1024
#define LOG2E 1.44269504088896f

// native f32->bf16 (RNE); compiler pairs these into v_cvt_pk_bf16_f32
__device__ __forceinline__ u16 b16(float f) {
  union { __bf16 h; u16 u; } cv; cv.h = (__bf16)f; return cv.u;
}

__device__ __forceinline__ void gload16(const void* g, void* l) {
  __builtin_amdgcn_global_load_lds(
      (const __attribute__((address_space(1))) uint32_t*)g,
      (__attribute__((address_space(3))) uint32_t*)l, 16, 0, 0);
}

// ---------------- f32 -> bf16 conversion ----------------
__global__ __launch_bounds__(256)
void cvt_bf16(const float* __restrict__ in, u16* __restrict__ out, int n) {
  int i = (blockIdx.x * 256 + threadIdx.x) * 4;
  if (i >= n) return;
  float4 v = *(const float4*)(in + i);
  u16x4 o = { b16(v.x), b16(v.y), b16(v.z), b16(v.w) };
  *(u16x4*)(out + i) = o;
}

// ---------------- RoPE cos/sin tables [S][32] ----------------
__global__ __launch_bounds__(256)
void rope_tab(float* __restrict__ ct, float* __restrict__ st) {
  int idx = blockIdx.x * 256 + threadIdx.x;
  if (idx >= S_LEN * 32) return;
  int s = idx >> 5, d = idx & 31;
  float inv = exp2f((float)d * (-13.287712379549449f / 32.0f));
  float a = (float)s * inv;
  ct[idx] = cosf(a);
  st[idx] = sinf(a);
}

// ---------------- GEMM: C = A(MxK) * B(NxK)^T, bf16 in, fused epilogues ----
// EPI 1: RoPE + (0.125*log2e) scale, store q [B,H,S,D] bf16
// EPI 2: RoPE, store k [B,H,S,D] bf16
// EPI 3: transpose-store v^T [B,H,D,S] bf16
// EPI 4: plain f32 store [M][N]
template<int EPI>
__global__ __launch_bounds__(256)
void gemm_bt(const u16* __restrict__ A, const u16* __restrict__ Bm,
             void* __restrict__ Cout,
             const float* __restrict__ ctab, const float* __restrict__ stab)
{
  __shared__ u16 sA[128 * 64];
  __shared__ u16 sB[128 * 64];
  const int tid  = threadIdx.x;
  const int lane = tid & 63;
  const int wid  = tid >> 6;
  const int wm   = wid >> 1, wn = wid & 1;
  const int lc   = lane & 15, lr = lane >> 4;
  const int tm   = blockIdx.y * 128;
  const int tn   = blockIdx.x * 128;

  f32x4 acc[4][4] = {};

  const u16* aS[4]; const u16* bS[4];
#pragma unroll
  for (int it = 0; it < 4; ++it) {
    int u = it * 256 + tid;
    int row = u >> 3;
    int ch  = (u & 7) ^ (row & 7);
    aS[it] = A  + (size_t)(tm + row) * DMODEL + ch * 8;
    bS[it] = Bm + (size_t)(tn + row) * DMODEL + ch * 8;
  }

  for (int k0 = 0; k0 < DMODEL; k0 += 64) {
    __syncthreads();
#pragma unroll
    for (int it = 0; it < 4; ++it) {
      int u = it * 256 + tid;
      gload16(aS[it] + k0, (char*)sA + u * 16);
      gload16(bS[it] + k0, (char*)sB + u * 16);
    }
    __syncthreads();
#pragma unroll
    for (int kk = 0; kk < 2; ++kk) {
      bf16x8 af[4], bq[4];
#pragma unroll
      for (int mi = 0; mi < 4; ++mi) {
        int row = wm * 64 + mi * 16 + lc;
        int ch  = (kk * 4 + lr) ^ (row & 7);
        af[mi] = *(const bf16x8*)((const char*)sA + row * 128 + ch * 16);
      }
#pragma unroll
      for (int ni = 0; ni < 4; ++ni) {
        int row = wn * 64 + ni * 16 + lc;
        int ch  = (kk * 4 + lr) ^ (row & 7);
        bq[ni] = *(const bf16x8*)((const char*)sB + row * 128 + ch * 16);
      }
#pragma unroll
      for (int mi = 0; mi < 4; ++mi)
#pragma unroll
        for (int ni = 0; ni < 4; ++ni)
          acc[mi][ni] = __builtin_amdgcn_mfma_f32_16x16x32_bf16(af[mi], bq[ni], acc[mi][ni], 0, 0, 0);
    }
  }

  if constexpr (EPI == 4) {
    float* C = (float*)Cout;
#pragma unroll
    for (int mi = 0; mi < 4; ++mi)
#pragma unroll
      for (int ni = 0; ni < 4; ++ni)
#pragma unroll
        for (int j = 0; j < 4; ++j) {
          int r = tm + wm * 64 + mi * 16 + lr * 4 + j;
          int c = tn + wn * 64 + ni * 16 + lc;
          C[(size_t)r * DMODEL + c] = acc[mi][ni][j];
        }
  } else if constexpr (EPI == 3) {
    u16* C = (u16*)Cout;   // v^T [B,H,D,S]
#pragma unroll
    for (int mi = 0; mi < 4; ++mi)
#pragma unroll
      for (int ni = 0; ni < 4; ++ni) {
        int col = tn + wn * 64 + ni * 16 + lc;
        int hh = col >> 6, d = col & 63;
        int m0 = tm + wm * 64 + mi * 16 + lr * 4;
        int bb = m0 >> 11, s = m0 & 2047;
        u16x4 v = { b16(acc[mi][ni][0]), b16(acc[mi][ni][1]),
                    b16(acc[mi][ni][2]), b16(acc[mi][ni][3]) };
        *(u16x4*)(C + (((size_t)bb * NHEADS + hh) * 64 + d) * S_LEN + s) = v;
      }
  } else {
    u16* C = (u16*)Cout;   // q/k [B,H,S,D], RoPE fused
#pragma unroll
    for (int mi = 0; mi < 4; ++mi)
#pragma unroll
      for (int ni = 0; ni < 2; ++ni)
#pragma unroll
        for (int j = 0; j < 4; ++j) {
          int col = tn + wn * 64 + ni * 16 + lc;
          int hh = col >> 6, dl = col & 63;
          int r = tm + wm * 64 + mi * 16 + lr * 4 + j;
          int bb = r >> 11, s = r & 2047;
          float x1 = acc[mi][ni][j], x2 = acc[mi][ni + 2][j];
          float cv = ctab[s * 32 + dl], sv = stab[s * 32 + dl];
          float o1 = x1 * cv - x2 * sv;
          float o2 = x1 * sv + x2 * cv;
          if constexpr (EPI == 1) {   // softmax scale * log2e folded into q
            o1 *= 0.125f * LOG2E; o2 *= 0.125f * LOG2E;
          }
          size_t base = (((size_t)bb * NHEADS + hh) * S_LEN + s) * 64 + dl;
          C[base]      = b16(o1);
          C[base + 32] = b16(o2);
        }
  }
}

// ---------------- fused causal attention with banded bias ----------------
// Swapped QK^T (lane holds one q-row), exp2-domain softmax, half-tile P in
// LDS (4 ds_write_b64 + 2 ds_read_b128 per tile; no bpermute), XCD-aware
// remap, balanced (31-pi, pi) pairing with shared KV sweep, T13 defer-rescale.
// LDS = 16K (K dbuf) + 16K (V dbuf) + 10K (P) + 4K (bias) = 46 KB -> 3 blk/CU.
__global__ __launch_bounds__(512, 6)
void attn_kernel(const u16* __restrict__ Q, const u16* __restrict__ K,
                 const u16* __restrict__ V, const float* __restrict__ biasg,
                 const float* __restrict__ offg, u16* __restrict__ O)
{
  __shared__ __align__(16) u16 sK[2][64 * 64];
  __shared__ __align__(16) u16 sV[2][64 * 64];
  __shared__ __align__(16) u16 sP[8][16 * 40];   // per-wave half-P [q][k<32], stride 40
  __shared__ float sBias[BIAS_LEN];

  const int tid = threadIdx.x, lane = tid & 63, wid = tid >> 6;
  const int lc = lane & 15, lr = lane >> 4;

  // XCD-aware remap: same-bh blocks land on one XCD (K/V fit its 4MB L2);
  // pi=0 (longest) dispatch first.
  const int L   = blockIdx.x;
  const int idx = L >> 3;
  const int pi  = idx >> 3;                 // 0..15
  const int bh  = (L & 7) + 8 * (idx & 7);  // 0..63
  const int h  = bh & 31;
  const int b  = bh >> 5;
  const int qtA  = 31 - pi;
  const int myQt = (wid < 4) ? qtA : pi;
  const int qw   = myQt * 64 + (wid & 3) * 16;   // wave's 16-row q base

  for (int i = tid; i < BIAS_LEN; i += 512) sBias[i] = biasg[h * BIAS_LEN + i] * LOG2E;
  const float off = offg[h] * LOG2E;

  // Q fragments (RoPE'd, scaled by 0.125*log2e). MFMA B-operand (swapped).
  const u16* qp = Q + ((size_t)bh * S_LEN + qw + lc) * 64;
  bf16x8 aq0 = *(const bf16x8*)(qp + lr * 8);
  bf16x8 aq1 = *(const bf16x8*)(qp + 32 + lr * 8);

  const int srow = tid >> 3;
  const int sch  = (tid & 7) ^ (srow & 7);
  const u16* kSrc = K + ((size_t)bh * S_LEN + srow) * 64 + sch * 8;
  const u16* vSrc = V + ((size_t)bh * 64 + srow) * S_LEN + sch * 8;

  float m = off, lsum = 1.0f;        // per-lane scalars for q = qw + lc (log2 domain)
  f32x4 o[4] = {};

  gload16(kSrc, (char*)sK[0] + tid * 16);
  gload16(vSrc, (char*)sV[0] + tid * 16);
  __syncthreads();

  for (int t = 0; t <= qtA; ++t) {
    const int cur = t & 1;
    if (t < qtA) {
      gload16(kSrc + (size_t)(t + 1) * 64 * 64, (char*)sK[cur ^ 1] + tid * 16);
      gload16(vSrc + (t + 1) * 64,              (char*)sV[cur ^ 1] + tid * 16);
    }

    if (t <= myQt) {
      const int kt = t * 64;
      // QK^T swapped: S^T[k][q] = K_rows x Q^T.
      f32x4 sc[4];
      __builtin_amdgcn_s_setprio(1);
#pragma unroll
      for (int f = 0; f < 4; ++f) {
        int row = f * 16 + lc;
        bf16x8 k0 = *(const bf16x8*)((const char*)sK[cur] + row * 128 + ((lr) ^ (row & 7)) * 16);
        bf16x8 k1 = *(const bf16x8*)((const char*)sK[cur] + row * 128 + ((4 + lr) ^ (row & 7)) * 16);
        f32x4 z = {};
        z     = __builtin_amdgcn_mfma_f32_16x16x32_bf16(k0, aq0, z, 0, 0, 0);
        sc[f] = __builtin_amdgcn_mfma_f32_16x16x32_bf16(k1, aq1, z, 0, 0, 0);
      }
      __builtin_amdgcn_s_setprio(0);

      // lane's q = qw + lc;  k = kt + koff,  koff = f*16 + lr*4 + j
      const int db  = qw + lc - kt;
      const int dqt = qw - kt;          // wave-uniform, multiple of 16
      float pvv[4][4];
      if (t == myQt) {                  // diagonal: causal mask, always in-band
#pragma unroll
        for (int f = 0; f < 4; ++f)
#pragma unroll
          for (int j = 0; j < 4; ++j) {
            int dd = db - (f * 16 + lr * 4 + j);
            float bb = sBias[dd & 1023];
            pvv[f][j] = (dd >= 0) ? sc[f][j] + bb : -1e30f;
          }
      } else if (dqt <= 1008) {         // interior, fully in-band: bias only
#pragma unroll
        for (int f = 0; f < 4; ++f)
#pragma unroll
          for (int j = 0; j < 4; ++j)
            pvv[f][j] = sc[f][j] + sBias[db - (f * 16 + lr * 4 + j)];
      } else if (dqt < 1088) {          // band edge: clip check only
#pragma unroll
        for (int f = 0; f < 4; ++f)
#pragma unroll
          for (int j = 0; j < 4; ++j) {
            int dd = db - (f * 16 + lr * 4 + j);
            float bb = (dd < 1024) ? sBias[dd & 1023] : 0.0f;
            pvv[f][j] = sc[f][j] + bb;
          }
      } else {                          // beyond band: raw scores
#pragma unroll
        for (int f = 0; f < 4; ++f)
#pragma unroll
          for (int j = 0; j < 4; ++j)
            pvv[f][j] = sc[f][j];
      }

      // row max: in-register tree + 2 shallow cross-lane steps
      float pmax = -1e30f;
#pragma unroll
      for (int f = 0; f < 4; ++f) {
        float a = fmaxf(fmaxf(pvv[f][0], pvv[f][1]), fmaxf(pvv[f][2], pvv[f][3]));
        pmax = fmaxf(pmax, a);
      }
      pmax = fmaxf(pmax, __shfl_xor(pmax, 16, 64));
      pmax = fmaxf(pmax, __shfl_xor(pmax, 32, 64));

      // T13 defer-rescale (log2 domain, THR=8 -> P bounded by 2^8)
      if (__any(pmax > m + 8.0f)) {
        float mn = fmaxf(m, pmax);
        float al = exp2f(m - mn);
        m = mn;
        lsum *= al;
        float aj[4];
#pragma unroll
        for (int j = 0; j < 4; ++j) aj[j] = __shfl(al, lr * 4 + j, 64);
#pragma unroll
        for (int f2 = 0; f2 < 4; ++f2)
#pragma unroll
          for (int j = 0; j < 4; ++j) o[f2][j] *= aj[j];
      }

      // exp2 + row-sum
      float rsum = 0.0f;
#pragma unroll
      for (int f = 0; f < 4; ++f)
#pragma unroll
        for (int j = 0; j < 4; ++j) {
          float p = exp2f(pvv[f][j] - m);
          pvv[f][j] = p;
          rsum += p;
        }
      rsum += __shfl_xor(rsum, 16, 64);
      rsum += __shfl_xor(rsum, 32, 64);
      lsum += rsum;

      // PV in two k-halves: write half-P (2 b64), wait LDS only (NOT vmcnt:
      // the prefetch must stay in flight), read A-frag (b128), 4 MFMAs.
      u16* myP = sP[wid];
#pragma unroll
      for (int kk = 0; kk < 2; ++kk) {
#pragma unroll
        for (int fl = 0; fl < 2; ++fl) {
          int f = kk * 2 + fl;
          u16x4 w = { b16(pvv[f][0]), b16(pvv[f][1]), b16(pvv[f][2]), b16(pvv[f][3]) };
          *(u16x4*)(myP + lc * 40 + fl * 16 + lr * 4) = w;
        }
        asm volatile("s_waitcnt lgkmcnt(0)" ::: "memory");
        __builtin_amdgcn_sched_barrier(0);
        bf16x8 ap = *(const bf16x8*)(myP + lc * 40 + lr * 8);
        __builtin_amdgcn_s_setprio(1);
#pragma unroll
        for (int f2 = 0; f2 < 4; ++f2) {
          int drow = f2 * 16 + lc;
          int chh = (kk * 4 + lr) ^ (drow & 7);
          bf16x8 bv = *(const bf16x8*)((const char*)sV[cur] + drow * 128 + chh * 16);
          o[f2] = __builtin_amdgcn_mfma_f32_16x16x32_bf16(ap, bv, o[f2], 0, 0, 0);
        }
        __builtin_amdgcn_s_setprio(0);
      }
    }
    __syncthreads();
  }

  // normalize + store [B,S,H,D] bf16
  float ls[4];
#pragma unroll
  for (int j = 0; j < 4; ++j) ls[j] = __shfl(lsum, lr * 4 + j, 64);
#pragma unroll
  for (int f2 = 0; f2 < 4; ++f2)
#pragma unroll
    for (int j = 0; j < 4; ++j) {
      int i = qw + lr * 4 + j;
      int d = f2 * 16 + lc;
      size_t addr = (((size_t)(b * S_LEN + i)) * NHEADS + h) * 64 + d;
      O[addr] = b16(o[f2][j] / ls[j]);
    }
}

// ---------------- launcher ----------------
extern "C" void kernel_launch(void* const* d_in, const int* in_sizes, int n_in,
                              void* d_out, int out_size, void* d_ws, size_t ws_size,
                              hipStream_t stream)
{
  const float* hs   = (const float*)d_in[0];
  const float* Wq   = (const float*)d_in[1];
  const float* Wk   = (const float*)d_in[2];
  const float* Wv   = (const float*)d_in[3];
  const float* Wo   = (const float*)d_in[4];
  const float* bias = (const float*)d_in[5];
  const float* off  = (const float*)d_in[6];

  char* p = (char*)d_ws;
  u16* hs_b = (u16*)p; p += (size_t)MROWS * DMODEL * 2;
  u16* wq_b = (u16*)p; p += (size_t)DMODEL * DMODEL * 2;
  u16* wk_b = (u16*)p; p += (size_t)DMODEL * DMODEL * 2;
  u16* wv_b = (u16*)p; p += (size_t)DMODEL * DMODEL * 2;
  u16* wo_b = (u16*)p; p += (size_t)DMODEL * DMODEL * 2;
  u16* qf   = (u16*)p; p += (size_t)MROWS * DMODEL * 2;
  u16* kf   = (u16*)p; p += (size_t)MROWS * DMODEL * 2;
  u16* vt   = (u16*)p; p += (size_t)MROWS * DMODEL * 2;
  u16* att  = (u16*)p; p += (size_t)MROWS * DMODEL * 2;
  float* ct = (float*)p; p += (size_t)S_LEN * 32 * 4;
  float* st = (float*)p; p += (size_t)S_LEN * 32 * 4;
  (void)ws_size; (void)in_sizes; (void)n_in; (void)out_size;

  cvt_bf16<<<(MROWS * DMODEL) / 1024, 256, 0, stream>>>(hs, hs_b, MROWS * DMODEL);
  cvt_bf16<<<(DMODEL * DMODEL) / 1024, 256, 0, stream>>>(Wq, wq_b, DMODEL * DMODEL);
  cvt_bf16<<<(DMODEL * DMODEL) / 1024, 256, 0, stream>>>(Wk, wk_b, DMODEL * DMODEL);
  cvt_bf16<<<(DMODEL * DMODEL) / 1024, 256, 0, stream>>>(Wv, wv_b, DMODEL * DMODEL);
  cvt_bf16<<<(DMODEL * DMODEL) / 1024, 256, 0, stream>>>(Wo, wo_b, DMODEL * DMODEL);
  rope_tab<<<(S_LEN * 32) / 256, 256, 0, stream>>>(ct, st);

  dim3 g(DMODEL / 128, MROWS / 128);
  gemm_bt<1><<<g, 256, 0, stream>>>(hs_b, wq_b, qf, ct, st);
  gemm_bt<2><<<g, 256, 0, stream>>>(hs_b, wk_b, kf, ct, st);
  gemm_bt<3><<<g, 256, 0, stream>>>(hs_b, wv_b, vt, nullptr, nullptr);
  attn_kernel<<<dim3(16 * 64), 512, 0, stream>>>(qf, kf, vt, bias, off, att);
  gemm_bt<4><<<g, 256, 0, stream>>>(att, wo_b, d_out, nullptr, nullptr);
}